// Round 7
// baseline (1228.304 us; speedup 1.0000x reference)
//
#include <hip/hip_runtime.h>

#define HH 50
#define NB 4            // batch elements per block -> grid 512 -> 2 blocks/CU (independent barriers)
#define TT 512
#define NTH 512
#define NT 13           // tiles of 4 units (52 >= 50)
#define AS 136          // shorts per activation row: 128 k-slots + 8 pad (272B; odd 16B-groups)
#define XS (TT * 3 + 4) // x-stash row stride (words)
#define NFRAG (NT * 12)

typedef __attribute__((ext_vector_type(8))) short short8;
typedef __attribute__((ext_vector_type(4))) float f32x4;

#define MFMA(a, b, c) __builtin_amdgcn_mfma_f32_16x16x32_bf16((a), (b), (c), 0, 0, 0)

__device__ __forceinline__ unsigned short f2bf(float f) {
    unsigned int u = __float_as_uint(f);
    u += 0x7FFFu + ((u >> 16) & 1u);
    return (unsigned short)(u >> 16);
}
__device__ __forceinline__ float bf2f(unsigned short s) {
    return __uint_as_float(((unsigned int)s) << 16);
}
// clamp-free: saturates correctly through inf (rcp(inf)=0), no NaN for finite v
__device__ __forceinline__ float fsig(float v) {
    return __builtin_amdgcn_rcpf(1.f + __builtin_amdgcn_exp2f(v * -1.442695041f));
}
__device__ __forceinline__ float ftanh(float v) {
    return fmaf(-2.f, __builtin_amdgcn_rcpf(1.f + __builtin_amdgcn_exp2f(v * 2.885390082f)), 1.f);
}

// ---------------- prep kernel: gate-interleaved A-operand weight fragments ----------------
// Tile nt covers units 4nt..4nt+3; row-in-tile r: unit = 4nt + (r>>2), gate = r&3.
// Slot map per tile: 0..3 = L0 kt{0,1}x{hi,lo} (K = [Whh0(50)|Wih0(3)|bias1|0..]);
//                    4..11 = L1 kt{0..3}x{hi,lo} (K = [Wih1(50)|Whh1(50)|bias1|0..]).
__global__ void prep_frags(
    const float* __restrict__ W_ih0, const float* __restrict__ W_hh0,
    const float* __restrict__ b_ih0, const float* __restrict__ b_hh0,
    const float* __restrict__ W_ih1, const float* __restrict__ W_hh1,
    const float* __restrict__ b_ih1, const float* __restrict__ b_hh1,
    unsigned short* __restrict__ ws)
{
    const int idx = blockIdx.x * blockDim.x + threadIdx.x;
    if (idx >= NFRAG * 64) return;
    const int lane = idx & 63;
    const int fid  = idx >> 6;
    const int nt   = fid / 12;
    const int slot = fid - nt * 12;
    const int r    = lane & 15;
    const int q    = lane >> 4;
    const int u    = nt * 4 + (r >> 2);
    const int gi   = r & 3;
    const int n    = gi * HH + u;          // original weight row
    const int layer = (slot < 4) ? 0 : 1;
    const int s     = (slot < 4) ? slot : (slot - 4);
    const int kt    = s >> 1;
    const int ishi  = !(s & 1);

    short8 v;
    #pragma unroll
    for (int jj = 0; jj < 8; ++jj) {
        const int k = kt * 32 + q * 8 + jj;
        float w = 0.f;
        if (u < HH) {
            if (layer == 0) {
                if (k < 50)       w = W_hh0[n * 50 + k];
                else if (k < 53)  w = W_ih0[n * 3 + (k - 50)];
                else if (k == 53) w = b_ih0[n] + b_hh0[n];
            } else {
                if (k < 50)        w = W_ih1[n * 50 + k];
                else if (k < 100)  w = W_hh1[n * 50 + (k - 50)];
                else if (k == 100) w = b_ih1[n] + b_hh1[n];
            }
        }
        const unsigned short h = f2bf(w);
        v[jj] = (short)(ishi ? h : f2bf(w - bf2f(h)));
    }
    *(short8*)&ws[((size_t)fid * 64 + lane) * 8] = v;
}

// ---------------- fused tile step: VERBATIM v10 numerics; only write guards widened ----------------
// Rows 4-7 / 12-15 of the A-array are permanently zero (NB=4): reads return 0, MFMA adds 0,
// cell lanes for those cols compute benign garbage (gate=0) and never write.
__device__ __forceinline__ void tile_step(
    const int nt, const int t,
    const short8* ah, const short8* al,
    const short8 w0h[2], const short8 w0l[2],
    const short8 w1h[4], const short8 w1l[4],
    float& cst, const int col, const int q4,
    unsigned short* dhi, unsigned short* dlo, float* hBf)
{
    f32x4 a0 = {0.f, 0.f, 0.f, 0.f}, a1 = {0.f, 0.f, 0.f, 0.f};
    #pragma unroll
    for (int kt = 0; kt < 2; ++kt) {                 // layer0 gates (K = 64)
        a0 = MFMA(w0h[kt], ah[kt], a0);
        a0 = MFMA(w0l[kt], ah[kt], a0);
        a0 = MFMA(w0h[kt], al[kt], a0);
    }
    #pragma unroll
    for (int kt = 0; kt < 4; ++kt) {                 // layer1 gates (K = 128)
        a1 = MFMA(w1h[kt], ah[kt], a1);
        a1 = MFMA(w1l[kt], ah[kt], a1);
        a1 = MFMA(w1h[kt], al[kt], a1);
    }
    const bool isL0 = (col < 8);
    const bool run = isL0 ? (t < TT) : (t > 0);      // uniform true for 0<t<TT
    if (run) {
        const float g0 = isL0 ? a0[0] : a1[0];
        const float g1 = isL0 ? a0[1] : a1[1];
        const float g2 = isL0 ? a0[2] : a1[2];
        const float g3 = isL0 ? a0[3] : a1[3];
        const float ii = fsig(g0), ff = fsig(g1);
        const float gg = ftanh(g2), oo = fsig(g3);
        const float c = ff * cst + ii * gg;
        cst = c;
        const float h = oo * ftanh(c);
        const int u = nt * 4 + q4;
        if (u < HH) {
            const unsigned short hh = f2bf(h);
            const unsigned short hl = f2bf(h - bf2f(hh));
            if (isL0) {
                if (col < NB) {                        // live L0 batches only
                    dhi[col * AS + u] = hh;            dlo[col * AS + u] = hl;        // L0 recurrent
                    dhi[(col + 8) * AS + u] = hh;      dlo[(col + 8) * AS + u] = hl;  // L1 input
                }
            } else {
                if (col < 8 + NB) {                    // live L1 batches only
                    dhi[col * AS + 50 + u] = hh;       dlo[col * AS + 50 + u] = hl;   // L1 recurrent
                    if (t == TT) hBf[(col - 8) * 52 + u] = h;
                }
            }
        }
    }
}

// ---------------- main kernel: v10 inner loop, NB=4, 2 independent blocks per CU ----------------
// v10-v13 evidence: within one barrier domain the phases (DS-read / MFMA / cell-VALU)
// serialize (sum ~= measured 2620 cy/step) and every inner-loop perturbation regresses.
// Fix: split the batch dimension so 2 blocks (separate barrier domains) share each CU --
// block A's cell phase overlaps block B's read/MFMA phase. Inner loop kept verbatim.
__global__ __launch_bounds__(NTH, 4) void lstm_mfma_v14(
    const float* __restrict__ x,
    const unsigned short* __restrict__ ws,
    const float* __restrict__ fc_w, const float* __restrict__ fc_b,
    float* __restrict__ out)
{
    __shared__ __align__(16) unsigned short Ahi[2][16 * AS];
    __shared__ __align__(16) unsigned short Alo[2][16 * AS];
    __shared__ float hBf[NB * 52];
    __shared__ unsigned int xstash[NB * XS];          // 4 x 1540 words = 24.6 KB

    const int tid  = threadIdx.x;
    const int lane = tid & 63;
    const int wid  = tid >> 6;
    const int col  = lane & 15;
    const int q4   = lane >> 4;
    const int b0   = blockIdx.x * NB;

    for (int i = tid; i < 16 * AS; i += NTH) {
        Ahi[0][i] = 0; Alo[0][i] = 0; Ahi[1][i] = 0; Alo[1][i] = 0;
    }

    // ---- preload + pre-split the block's x slab (contiguous 24 KB) ----
    {
        const float* xg = x + (size_t)b0 * (TT * 3);
        for (int i = tid; i < (NB * TT * 3) / 4; i += NTH) {   // 1536 float4s, 3 iters
            const float4 v4 = ((const float4*)xg)[i];
            const int e = i * 4;
            #pragma unroll
            for (int j = 0; j < 4; ++j) {
                const float v = (&v4.x)[j];
                const int b = (e + j) / (TT * 3);
                const int r = (e + j) - b * (TT * 3);
                const unsigned short h = f2bf(v);
                const unsigned short l = f2bf(v - bf2f(h));
                xstash[b * XS + r] = (unsigned int)h | ((unsigned int)l << 16);
            }
        }
    }
    __syncthreads();

    if (tid < NB) {                                   // bias columns, both buffers
        Ahi[0][tid * AS + 53] = 0x3F80;        Ahi[1][tid * AS + 53] = 0x3F80;
        Ahi[0][(tid + 8) * AS + 100] = 0x3F80; Ahi[1][(tid + 8) * AS + 100] = 0x3F80;
    }

    // ---- weight fragments: wave w owns tile w, plus tile 8+w if w<5 ----
    const short8* wsf = (const short8*)ws;
    short8 w0h[2][2], w0l[2][2], w1h[2][4], w1l[2][4];
    const bool has2 = (wid < 5);
    #pragma unroll
    for (int i = 0; i < 2; ++i) {
        const int nt = (i == 0) ? wid : 8 + wid;
        const bool v = (i == 0) || has2;
        const size_t gb = (size_t)(v ? nt : 0) * (12 * 64) + lane;
        #pragma unroll
        for (int kt = 0; kt < 2; ++kt) {
            w0h[i][kt] = v ? wsf[gb + (size_t)(kt * 2 + 0) * 64] : short8{};
            w0l[i][kt] = v ? wsf[gb + (size_t)(kt * 2 + 1) * 64] : short8{};
        }
        #pragma unroll
        for (int kt = 0; kt < 4; ++kt) {
            w1h[i][kt] = v ? wsf[gb + (size_t)(4 + kt * 2 + 0) * 64] : short8{};
            w1l[i][kt] = v ? wsf[gb + (size_t)(4 + kt * 2 + 1) * 64] : short8{};
        }
    }

    // ---- x-writer role: wave 7 lanes 0..11 (1-tile wave) ----
    int xb = 0, xc = 0, xoff = 0;
    const bool isx = (tid >= 448 && tid < 448 + NB * 3);
    if (isx) {
        const int i = tid - 448;
        xb = i / 3; xc = i - xb * 3;
        xoff = xb * AS + 50 + xc;
        const unsigned int w0 = xstash[xb * XS + xc];          // x(0) -> buf 0
        Ahi[0][xoff] = (unsigned short)(w0 & 0xFFFFu);
        Alo[0][xoff] = (unsigned short)(w0 >> 16);
    }
    float cst0 = 0.f, cst1 = 0.f;                     // c-state per owned tile
    __syncthreads();

    const int rbase = col * AS + q4 * 8;

    // ======== single-phase main loop: read buf p, write buf p^1, ONE barrier ========
    for (int t = 0; t <= TT; ++t) {
        const int p = t & 1;
        unsigned short* shi = Ahi[p];
        unsigned short* slo = Alo[p];
        unsigned short* dhi = Ahi[p ^ 1];
        unsigned short* dlo = Alo[p ^ 1];

        short8 ah[4], al[4];                          // B-operand activation frags (verbatim v10)
        #pragma unroll
        for (int kt = 0; kt < 4; ++kt) {
            ah[kt] = *(const short8*)&shi[rbase + kt * 32];
            al[kt] = *(const short8*)&slo[rbase + kt * 32];
        }

        tile_step(wid, t, ah, al, w0h[0], w0l[0], w1h[0], w1l[0], cst0, col, q4, dhi, dlo, hBf);
        if (has2)
            tile_step(8 + wid, t, ah, al, w0h[1], w0l[1], w1h[1], w1l[1], cst1, col, q4, dhi, dlo, hBf);

        if (isx) {                                    // stage x(t+1) from LDS stash (no vmem)
            const int tn1 = (t + 1 < TT) ? (t + 1) : (TT - 1);
            const unsigned int wrd = xstash[xb * XS + tn1 * 3 + xc];
            dhi[xoff] = (unsigned short)(wrd & 0xFFFFu);
            dlo[xoff] = (unsigned short)(wrd >> 16);
        }
        __syncthreads();
    }

    // ======== final FC ========
    if (tid < NB * 3) {
        const int bb = tid / 3, o = tid - bb * 3;
        float a = fc_b[o];
        #pragma unroll
        for (int uu = 0; uu < HH; ++uu)
            a += hBf[bb * 52 + uu] * fc_w[o * HH + uu];
        out[(size_t)(b0 + bb) * 3 + o] = a;
    }
}

extern "C" void kernel_launch(void* const* d_in, const int* in_sizes, int n_in,
                              void* d_out, int out_size, void* d_ws, size_t ws_size,
                              hipStream_t stream) {
    const float* x     = (const float*)d_in[0];
    const float* W_ih0 = (const float*)d_in[1];
    const float* W_hh0 = (const float*)d_in[2];
    const float* b_ih0 = (const float*)d_in[3];
    const float* b_hh0 = (const float*)d_in[4];
    const float* W_ih1 = (const float*)d_in[5];
    const float* W_hh1 = (const float*)d_in[6];
    const float* b_ih1 = (const float*)d_in[7];
    const float* b_hh1 = (const float*)d_in[8];
    const float* fc_w  = (const float*)d_in[9];
    const float* fc_b  = (const float*)d_in[10];
    float* out = (float*)d_out;
    unsigned short* ws = (unsigned short*)d_ws;       // NFRAG*64*16 B = 156 KB

    const int prepN = NFRAG * 64;
    prep_frags<<<(prepN + 255) / 256, 256, 0, stream>>>(
        W_ih0, W_hh0, b_ih0, b_hh0, W_ih1, W_hh1, b_ih1, b_hh1, ws);

    const int B = 2048;
    dim3 grid(B / NB), block(NTH);                    // 512 blocks -> 2 per CU
    lstm_mfma_v14<<<grid, block, 0, stream>>>(x, ws, fc_w, fc_b, out);
}

// Round 8
// 488.394 us; speedup vs baseline: 2.5150x; 2.5150x over previous
//
#include <hip/hip_runtime.h>

#define HH 50
#define NB 8            // batch elements per block
#define TT 512
#define NTH 512
#define NT 13           // tiles of 4 units (52 >= 50)
#define AS 136          // shorts per activation row: 128 k-slots + 8 pad (272B; odd 16B-groups)
#define XS (TT * 3 + 4) // x-stash row stride (fp16 elements)
#define NFRAG (NT * 12)

typedef __attribute__((ext_vector_type(8))) _Float16 half8;
typedef __attribute__((ext_vector_type(4))) float f32x4;

#define MFMA16(a, b, c) __builtin_amdgcn_mfma_f32_16x16x32_f16((a), (b), (c), 0, 0, 0)

// w_lo stored pre-scaled by 2048; folded back with one fma per gate component
#define WLO_SCALE 2048.0f
#define WLO_INV   4.8828125e-4f   // exact 1/2048

__device__ __forceinline__ unsigned short f2h(float f) {
    const _Float16 h = (_Float16)f;               // v_cvt_f16_f32, RTNE
    return __builtin_bit_cast(unsigned short, h);
}
// clamp-free: saturates correctly through inf (rcp(inf)=0), no NaN for finite v
__device__ __forceinline__ float fsig(float v) {
    return __builtin_amdgcn_rcpf(1.f + __builtin_amdgcn_exp2f(v * -1.442695041f));
}
__device__ __forceinline__ float ftanh(float v) {
    return fmaf(-2.f, __builtin_amdgcn_rcpf(1.f + __builtin_amdgcn_exp2f(v * 2.885390082f)), 1.f);
}

// ---------------- prep kernel: gate-interleaved fp16 A-operand weight fragments ----------------
// Tile nt covers units 4nt..4nt+3; row-in-tile r: unit = 4nt + (r>>2), gate = r&3.
// Slot map per tile (unchanged layout, fp16 content; lo = (W - fp16(W)) * 2048):
//   0..3 = L0 kt{0,1}x{hi,lo} (K = [Whh0(50)|Wih0(3)|bias1|0..]);
//   4..11 = L1 kt{0..3}x{hi,lo} (K = [Wih1(50)|Whh1(50)|bias1|0..]).
__global__ void prep_frags(
    const float* __restrict__ W_ih0, const float* __restrict__ W_hh0,
    const float* __restrict__ b_ih0, const float* __restrict__ b_hh0,
    const float* __restrict__ W_ih1, const float* __restrict__ W_hh1,
    const float* __restrict__ b_ih1, const float* __restrict__ b_hh1,
    unsigned short* __restrict__ ws)
{
    const int idx = blockIdx.x * blockDim.x + threadIdx.x;
    if (idx >= NFRAG * 64) return;
    const int lane = idx & 63;
    const int fid  = idx >> 6;
    const int nt   = fid / 12;
    const int slot = fid - nt * 12;
    const int r    = lane & 15;
    const int q    = lane >> 4;
    const int u    = nt * 4 + (r >> 2);
    const int gi   = r & 3;
    const int n    = gi * HH + u;          // original weight row
    const int layer = (slot < 4) ? 0 : 1;
    const int s     = (slot < 4) ? slot : (slot - 4);
    const int kt    = s >> 1;
    const int ishi  = !(s & 1);

    unsigned short v[8];
    #pragma unroll
    for (int jj = 0; jj < 8; ++jj) {
        const int k = kt * 32 + q * 8 + jj;
        float w = 0.f;
        if (u < HH) {
            if (layer == 0) {
                if (k < 50)       w = W_hh0[n * 50 + k];
                else if (k < 53)  w = W_ih0[n * 3 + (k - 50)];
                else if (k == 53) w = b_ih0[n] + b_hh0[n];
            } else {
                if (k < 50)        w = W_ih1[n * 50 + k];
                else if (k < 100)  w = W_hh1[n * 50 + (k - 50)];
                else if (k == 100) w = b_ih1[n] + b_hh1[n];
            }
        }
        if (ishi) {
            v[jj] = f2h(w);
        } else {
            const float hi = (float)(_Float16)w;
            v[jj] = f2h((w - hi) * WLO_SCALE);
        }
    }
    #pragma unroll
    for (int jj = 0; jj < 8; ++jj)
        ws[((size_t)fid * 64 + lane) * 8 + jj] = v[jj];
}

// ---------------- fused tile step: fp16 MFMA (main + scaled-corr) -> cell -> fp16 writeback ----------------
// 12 MFMA/tile (was 18), 4 independent chains of depth 2/2/4/4.
__device__ __forceinline__ void tile_step(
    const int nt, const int t,
    const half8 ah[4],
    const half8 w0h[2], const half8 w0l[2],
    const half8 w1h[4], const half8 w1l[4],
    float& cst, const int col, const int q4,
    unsigned short* dA, float* hBf)
{
    f32x4 m0 = {0.f,0.f,0.f,0.f}, c0 = {0.f,0.f,0.f,0.f};
    f32x4 m1 = {0.f,0.f,0.f,0.f}, c1 = {0.f,0.f,0.f,0.f};
    #pragma unroll
    for (int kt = 0; kt < 2; ++kt) {                 // layer0 gates (K = 64)
        m0 = MFMA16(w0h[kt], ah[kt], m0);
        c0 = MFMA16(w0l[kt], ah[kt], c0);
    }
    #pragma unroll
    for (int kt = 0; kt < 4; ++kt) {                 // layer1 gates (K = 128)
        m1 = MFMA16(w1h[kt], ah[kt], m1);
        c1 = MFMA16(w1l[kt], ah[kt], c1);
    }
    const f32x4 a0 = m0 + c0 * WLO_INV;              // fold scaled weight-lo correction
    const f32x4 a1 = m1 + c1 * WLO_INV;

    const bool isL0 = (col < 8);
    const bool run = isL0 ? (t < TT) : (t > 0);      // uniform true for 0<t<TT
    if (run) {
        const float g0 = isL0 ? a0[0] : a1[0];
        const float g1 = isL0 ? a0[1] : a1[1];
        const float g2 = isL0 ? a0[2] : a1[2];
        const float g3 = isL0 ? a0[3] : a1[3];
        const float ii = fsig(g0), ff = fsig(g1);
        const float gg = ftanh(g2), oo = fsig(g3);
        const float c = ff * cst + ii * gg;
        cst = c;
        const float h = oo * ftanh(c);
        const int u = nt * 4 + q4;
        if (u < HH) {
            const unsigned short hs = f2h(h);
            if (isL0) {
                dA[col * AS + u] = hs;               // L0 recurrent
                dA[(col + 8) * AS + u] = hs;         // L1 input
            } else {
                dA[col * AS + 50 + u] = hs;          // L1 recurrent
                if (t == TT) hBf[(col - 8) * 52 + u] = h;
            }
        }
    }
}

// ---------------- main kernel: v10 structure, single-fp16 activations ----------------
// v11-v14 lesson: step time tracks DS-read INSTRUCTION count; only deleting work wins.
// fp16 (10-bit mantissa) replaces the bf16 hi/lo pair: reads 8->4 b128/wave, MFMA
// 18->12/tile, h-writeback halved, cell lo-extraction gone. Weights keep a Dekker
// split in fp16 (lo pre-scaled x2048, one fma to fold). Structure/roles/barrier = v10.
__global__ __launch_bounds__(NTH, 2) void lstm_mfma_v15(
    const float* __restrict__ x,
    const unsigned short* __restrict__ ws,
    const float* __restrict__ fc_w, const float* __restrict__ fc_b,
    float* __restrict__ out)
{
    __shared__ __align__(16) unsigned short Ah[2][16 * AS];
    __shared__ float hBf[NB * 52];
    __shared__ unsigned short xstash[NB * XS];        // 8 x 1540 fp16 = 24.6 KB

    const int tid  = threadIdx.x;
    const int lane = tid & 63;
    const int wid  = tid >> 6;
    const int col  = lane & 15;
    const int q4   = lane >> 4;
    const int b0   = blockIdx.x * NB;

    for (int i = tid; i < 16 * AS; i += NTH) {
        Ah[0][i] = 0; Ah[1][i] = 0;
    }

    // ---- preload + fp16-convert the block's x slab (contiguous 48 KB) ----
    {
        const float* xg = x + (size_t)b0 * (TT * 3);
        for (int i = tid; i < (NB * TT * 3) / 4; i += NTH) {   // 3072 float4s, 6 iters
            const float4 v4 = ((const float4*)xg)[i];
            const int e = i * 4;
            #pragma unroll
            for (int j = 0; j < 4; ++j) {
                const int b = (e + j) / (TT * 3);
                const int r = (e + j) - b * (TT * 3);
                xstash[b * XS + r] = f2h((&v4.x)[j]);
            }
        }
    }
    __syncthreads();

    if (tid < NB) {                                   // bias columns (fp16 1.0), both buffers
        Ah[0][tid * AS + 53] = 0x3C00;        Ah[1][tid * AS + 53] = 0x3C00;
        Ah[0][(tid + 8) * AS + 100] = 0x3C00; Ah[1][(tid + 8) * AS + 100] = 0x3C00;
    }

    // ---- weight fragments: wave w owns tile w, plus tile 8+w if w<5 ----
    const half8* wsf = (const half8*)ws;
    half8 w0h[2][2], w0l[2][2], w1h[2][4], w1l[2][4];
    const bool has2 = (wid < 5);
    #pragma unroll
    for (int i = 0; i < 2; ++i) {
        const int nt = (i == 0) ? wid : 8 + wid;
        const bool v = (i == 0) || has2;
        const size_t gb = (size_t)(v ? nt : 0) * (12 * 64) + lane;
        #pragma unroll
        for (int kt = 0; kt < 2; ++kt) {
            w0h[i][kt] = v ? wsf[gb + (size_t)(kt * 2 + 0) * 64] : half8{};
            w0l[i][kt] = v ? wsf[gb + (size_t)(kt * 2 + 1) * 64] : half8{};
        }
        #pragma unroll
        for (int kt = 0; kt < 4; ++kt) {
            w1h[i][kt] = v ? wsf[gb + (size_t)(4 + kt * 2 + 0) * 64] : half8{};
            w1l[i][kt] = v ? wsf[gb + (size_t)(4 + kt * 2 + 1) * 64] : half8{};
        }
    }

    // ---- x-writer role: wave 7 lanes 0..23 (1-tile wave) ----
    int xb = 0, xc = 0, xoff = 0;
    const bool isx = (tid >= 448 && tid < 448 + NB * 3);
    if (isx) {
        const int i = tid - 448;
        xb = i / 3; xc = i - xb * 3;
        xoff = xb * AS + 50 + xc;
        Ah[0][xoff] = xstash[xb * XS + xc];           // x(0) -> buf 0
    }
    float cst0 = 0.f, cst1 = 0.f;                     // c-state per owned tile
    __syncthreads();

    const int rbase = col * AS + q4 * 8;

    // ======== single-phase main loop: read buf p, write buf p^1, ONE barrier ========
    for (int t = 0; t <= TT; ++t) {
        const int p = t & 1;
        const unsigned short* sA = Ah[p];
        unsigned short* dA = Ah[p ^ 1];

        half8 ah[4];                                  // B-operand activation frags (4 reads!)
        #pragma unroll
        for (int kt = 0; kt < 4; ++kt)
            ah[kt] = *(const half8*)&sA[rbase + kt * 32];

        tile_step(wid, t, ah, w0h[0], w0l[0], w1h[0], w1l[0], cst0, col, q4, dA, hBf);
        if (has2)
            tile_step(8 + wid, t, ah, w0h[1], w0l[1], w1h[1], w1l[1], cst1, col, q4, dA, hBf);

        if (isx) {                                    // stage x(t+1) from LDS stash (no vmem)
            const int tn1 = (t + 1 < TT) ? (t + 1) : (TT - 1);
            dA[xoff] = xstash[xb * XS + tn1 * 3 + xc];
        }
        __syncthreads();
    }

    // ======== final FC ========
    if (tid < NB * 3) {
        const int bb = tid / 3, o = tid - bb * 3;
        float a = fc_b[o];
        #pragma unroll
        for (int uu = 0; uu < HH; ++uu)
            a += hBf[bb * 52 + uu] * fc_w[o * HH + uu];
        out[(size_t)(b0 + bb) * 3 + o] = a;
    }
}

extern "C" void kernel_launch(void* const* d_in, const int* in_sizes, int n_in,
                              void* d_out, int out_size, void* d_ws, size_t ws_size,
                              hipStream_t stream) {
    const float* x     = (const float*)d_in[0];
    const float* W_ih0 = (const float*)d_in[1];
    const float* W_hh0 = (const float*)d_in[2];
    const float* b_ih0 = (const float*)d_in[3];
    const float* b_hh0 = (const float*)d_in[4];
    const float* W_ih1 = (const float*)d_in[5];
    const float* W_hh1 = (const float*)d_in[6];
    const float* b_ih1 = (const float*)d_in[7];
    const float* b_hh1 = (const float*)d_in[8];
    const float* fc_w  = (const float*)d_in[9];
    const float* fc_b  = (const float*)d_in[10];
    float* out = (float*)d_out;
    unsigned short* ws = (unsigned short*)d_ws;       // NFRAG*64*16 B = 156 KB

    const int prepN = NFRAG * 64;
    prep_frags<<<(prepN + 255) / 256, 256, 0, stream>>>(
        W_ih0, W_hh0, b_ih0, b_hh0, W_ih1, W_hh1, b_ih1, b_hh1, ws);

    const int B = 2048;
    dim3 grid(B / NB), block(NTH);
    lstm_mfma_v15<<<grid, block, 0, stream>>>(x, ws, fc_w, fc_b, out);
}

// Round 9
// 376.468 us; speedup vs baseline: 3.2627x; 1.2973x over previous
//
#include <hip/hip_runtime.h>

#define HH 50
#define NB 8            // batch elements per block
#define TT 512
#define NTH 512
#define NT 13           // tiles of 4 units (52 >= 50)
#define AS 136          // shorts per activation row: 128 k-slots + 8 pad (272B; odd 16B-groups)
#define XS (TT * 3 + 4) // x-stash row stride (fp16 elements)
#define NFRAG (NT * 12)

typedef __attribute__((ext_vector_type(8))) _Float16 half8;
typedef __attribute__((ext_vector_type(4))) float f32x4;

#define MFMA16(a, b, c) __builtin_amdgcn_mfma_f32_16x16x32_f16((a), (b), (c), 0, 0, 0)

// lo slots still produced by prep (layout unchanged) but no longer consumed:
// activation-path fp16 quantization (~2^-11) already dominates the error budget,
// so the weight-lo correction MFMAs are deleted (12 -> 6 MFMA per tile).
#define WLO_SCALE 2048.0f

__device__ __forceinline__ unsigned short f2h(float f) {
    const _Float16 h = (_Float16)f;               // v_cvt_f16_f32, RTNE
    return __builtin_bit_cast(unsigned short, h);
}
// clamp-free: saturates correctly through inf (rcp(inf)=0), no NaN for finite v
__device__ __forceinline__ float fsig(float v) {
    return __builtin_amdgcn_rcpf(1.f + __builtin_amdgcn_exp2f(v * -1.442695041f));
}
__device__ __forceinline__ float ftanh(float v) {
    return fmaf(-2.f, __builtin_amdgcn_rcpf(1.f + __builtin_amdgcn_exp2f(v * 2.885390082f)), 1.f);
}

// ---------------- prep kernel: gate-interleaved fp16 A-operand weight fragments ----------------
// (unchanged from v15; lo slots written but unused by the main kernel)
__global__ void prep_frags(
    const float* __restrict__ W_ih0, const float* __restrict__ W_hh0,
    const float* __restrict__ b_ih0, const float* __restrict__ b_hh0,
    const float* __restrict__ W_ih1, const float* __restrict__ W_hh1,
    const float* __restrict__ b_ih1, const float* __restrict__ b_hh1,
    unsigned short* __restrict__ ws)
{
    const int idx = blockIdx.x * blockDim.x + threadIdx.x;
    if (idx >= NFRAG * 64) return;
    const int lane = idx & 63;
    const int fid  = idx >> 6;
    const int nt   = fid / 12;
    const int slot = fid - nt * 12;
    const int r    = lane & 15;
    const int q    = lane >> 4;
    const int u    = nt * 4 + (r >> 2);
    const int gi   = r & 3;
    const int n    = gi * HH + u;          // original weight row
    const int layer = (slot < 4) ? 0 : 1;
    const int s     = (slot < 4) ? slot : (slot - 4);
    const int kt    = s >> 1;
    const int ishi  = !(s & 1);

    unsigned short v[8];
    #pragma unroll
    for (int jj = 0; jj < 8; ++jj) {
        const int k = kt * 32 + q * 8 + jj;
        float w = 0.f;
        if (u < HH) {
            if (layer == 0) {
                if (k < 50)       w = W_hh0[n * 50 + k];
                else if (k < 53)  w = W_ih0[n * 3 + (k - 50)];
                else if (k == 53) w = b_ih0[n] + b_hh0[n];
            } else {
                if (k < 50)        w = W_ih1[n * 50 + k];
                else if (k < 100)  w = W_hh1[n * 50 + (k - 50)];
                else if (k == 100) w = b_ih1[n] + b_hh1[n];
            }
        }
        if (ishi) {
            v[jj] = f2h(w);
        } else {
            const float hi = (float)(_Float16)w;
            v[jj] = f2h((w - hi) * WLO_SCALE);
        }
    }
    #pragma unroll
    for (int jj = 0; jj < 8; ++jj)
        ws[((size_t)fid * 64 + lane) * 8 + jj] = v[jj];
}

// ---------------- fused tile step: 6 fp16 MFMA -> cell -> fp16 writeback ----------------
// Chains: a0 depth 2, a1 depth 4 (single hi stream each; no correction, no fold).
__device__ __forceinline__ void tile_step(
    const int nt, const int t,
    const half8 ah[4],
    const half8 w0h[2], const half8 w1h[4],
    float& cst, const int col, const int q4,
    unsigned short* dA, float* hBf)
{
    f32x4 a0 = {0.f,0.f,0.f,0.f};
    f32x4 a1 = {0.f,0.f,0.f,0.f};
    #pragma unroll
    for (int kt = 0; kt < 2; ++kt)                   // layer0 gates (K = 64)
        a0 = MFMA16(w0h[kt], ah[kt], a0);
    #pragma unroll
    for (int kt = 0; kt < 4; ++kt)                   // layer1 gates (K = 128)
        a1 = MFMA16(w1h[kt], ah[kt], a1);

    const bool isL0 = (col < 8);
    const bool run = isL0 ? (t < TT) : (t > 0);      // uniform true for 0<t<TT
    if (run) {
        const float g0 = isL0 ? a0[0] : a1[0];
        const float g1 = isL0 ? a0[1] : a1[1];
        const float g2 = isL0 ? a0[2] : a1[2];
        const float g3 = isL0 ? a0[3] : a1[3];
        const float ii = fsig(g0), ff = fsig(g1);
        const float gg = ftanh(g2), oo = fsig(g3);
        const float c = ff * cst + ii * gg;
        cst = c;
        const float h = oo * ftanh(c);
        const int u = nt * 4 + q4;
        if (u < HH) {
            const unsigned short hs = f2h(h);
            if (isL0) {
                dA[col * AS + u] = hs;               // L0 recurrent
                dA[(col + 8) * AS + u] = hs;         // L1 input
            } else {
                dA[col * AS + 50 + u] = hs;          // L1 recurrent
                if (t == TT) hBf[(col - 8) * 52 + u] = h;
            }
        }
    }
}

// ---------------- main kernel: v15 structure, hi-only fp16 weights (6 MFMA/tile) ----------------
__global__ __launch_bounds__(NTH, 2) void lstm_mfma_v16(
    const float* __restrict__ x,
    const unsigned short* __restrict__ ws,
    const float* __restrict__ fc_w, const float* __restrict__ fc_b,
    float* __restrict__ out)
{
    __shared__ __align__(16) unsigned short Ah[2][16 * AS];
    __shared__ float hBf[NB * 52];
    __shared__ unsigned short xstash[NB * XS];        // 8 x 1540 fp16 = 24.6 KB

    const int tid  = threadIdx.x;
    const int lane = tid & 63;
    const int wid  = tid >> 6;
    const int col  = lane & 15;
    const int q4   = lane >> 4;
    const int b0   = blockIdx.x * NB;

    for (int i = tid; i < 16 * AS; i += NTH) {
        Ah[0][i] = 0; Ah[1][i] = 0;
    }

    // ---- preload + fp16-convert the block's x slab (contiguous 48 KB) ----
    {
        const float* xg = x + (size_t)b0 * (TT * 3);
        for (int i = tid; i < (NB * TT * 3) / 4; i += NTH) {   // 3072 float4s, 6 iters
            const float4 v4 = ((const float4*)xg)[i];
            const int e = i * 4;
            #pragma unroll
            for (int j = 0; j < 4; ++j) {
                const int b = (e + j) / (TT * 3);
                const int r = (e + j) - b * (TT * 3);
                xstash[b * XS + r] = f2h((&v4.x)[j]);
            }
        }
    }
    __syncthreads();

    if (tid < NB) {                                   // bias columns (fp16 1.0), both buffers
        Ah[0][tid * AS + 53] = 0x3C00;        Ah[1][tid * AS + 53] = 0x3C00;
        Ah[0][(tid + 8) * AS + 100] = 0x3C00; Ah[1][(tid + 8) * AS + 100] = 0x3C00;
    }

    // ---- weight fragments (hi only): wave w owns tile w, plus tile 8+w if w<5 ----
    const half8* wsf = (const half8*)ws;
    half8 w0h[2][2], w1h[2][4];
    const bool has2 = (wid < 5);
    #pragma unroll
    for (int i = 0; i < 2; ++i) {
        const int nt = (i == 0) ? wid : 8 + wid;
        const bool v = (i == 0) || has2;
        const size_t gb = (size_t)(v ? nt : 0) * (12 * 64) + lane;
        #pragma unroll
        for (int kt = 0; kt < 2; ++kt)
            w0h[i][kt] = v ? wsf[gb + (size_t)(kt * 2 + 0) * 64] : half8{};
        #pragma unroll
        for (int kt = 0; kt < 4; ++kt)
            w1h[i][kt] = v ? wsf[gb + (size_t)(4 + kt * 2 + 0) * 64] : half8{};
    }

    // ---- x-writer role: wave 7 lanes 0..23 (1-tile wave) ----
    int xb = 0, xc = 0, xoff = 0;
    const bool isx = (tid >= 448 && tid < 448 + NB * 3);
    if (isx) {
        const int i = tid - 448;
        xb = i / 3; xc = i - xb * 3;
        xoff = xb * AS + 50 + xc;
        Ah[0][xoff] = xstash[xb * XS + xc];           // x(0) -> buf 0
    }
    float cst0 = 0.f, cst1 = 0.f;                     // c-state per owned tile
    __syncthreads();

    const int rbase = col * AS + q4 * 8;

    // ======== single-phase main loop: read buf p, write buf p^1, ONE barrier ========
    for (int t = 0; t <= TT; ++t) {
        const int p = t & 1;
        const unsigned short* sA = Ah[p];
        unsigned short* dA = Ah[p ^ 1];

        half8 ah[4];                                  // B-operand activation frags
        #pragma unroll
        for (int kt = 0; kt < 4; ++kt)
            ah[kt] = *(const half8*)&sA[rbase + kt * 32];

        tile_step(wid, t, ah, w0h[0], w1h[0], cst0, col, q4, dA, hBf);
        if (has2)
            tile_step(8 + wid, t, ah, w0h[1], w1h[1], cst1, col, q4, dA, hBf);

        if (isx) {                                    // stage x(t+1) from LDS stash (no vmem)
            const int tn1 = (t + 1 < TT) ? (t + 1) : (TT - 1);
            dA[xoff] = xstash[xb * XS + tn1 * 3 + xc];
        }
        __syncthreads();
    }

    // ======== final FC ========
    if (tid < NB * 3) {
        const int bb = tid / 3, o = tid - bb * 3;
        float a = fc_b[o];
        #pragma unroll
        for (int uu = 0; uu < HH; ++uu)
            a += hBf[bb * 52 + uu] * fc_w[o * HH + uu];
        out[(size_t)(b0 + bb) * 3 + o] = a;
    }
}

extern "C" void kernel_launch(void* const* d_in, const int* in_sizes, int n_in,
                              void* d_out, int out_size, void* d_ws, size_t ws_size,
                              hipStream_t stream) {
    const float* x     = (const float*)d_in[0];
    const float* W_ih0 = (const float*)d_in[1];
    const float* W_hh0 = (const float*)d_in[2];
    const float* b_ih0 = (const float*)d_in[3];
    const float* b_hh0 = (const float*)d_in[4];
    const float* W_ih1 = (const float*)d_in[5];
    const float* W_hh1 = (const float*)d_in[6];
    const float* b_ih1 = (const float*)d_in[7];
    const float* b_hh1 = (const float*)d_in[8];
    const float* fc_w  = (const float*)d_in[9];
    const float* fc_b  = (const float*)d_in[10];
    float* out = (float*)d_out;
    unsigned short* ws = (unsigned short*)d_ws;       // NFRAG*64*16 B = 156 KB

    const int prepN = NFRAG * 64;
    prep_frags<<<(prepN + 255) / 256, 256, 0, stream>>>(
        W_ih0, W_hh0, b_ih0, b_hh0, W_ih1, W_hh1, b_ih1, b_hh1, ws);

    const int B = 2048;
    dim3 grid(B / NB), block(NTH);
    lstm_mfma_v16<<<grid, block, 0, stream>>>(x, ws, fc_w, fc_b, out);
}